// Round 4
// baseline (326.181 us; speedup 1.0000x reference)
//
#include <hip/hip_runtime.h>

#define Bn 4
#define Nn 40
#define NCUBE 64000   // 40^3
#define ROWS 64       // rows per tile
#define BPB  1000     // full/dense-sums blocks per batch
#define MAXV 16384    // valid-row list capacity per batch (>= C(40,3)=9880)
#define CBLK 160      // compact-sums blocks per batch

typedef _Float16 f16;
typedef __attribute__((ext_vector_type(8))) _Float16 f16x8;
typedef __attribute__((ext_vector_type(4))) _Float16 f16x4;
typedef __attribute__((ext_vector_type(4))) float f32x4;

// ---------------- workspace layout (bytes) ----------------
// 0      : sums[Bn*128] f32
// 2048   : cnt[Bn] int
// 4096   : vlist[Bn*MAXV] int        (compact tier only)
// WBOFF  : f16 weight fragments (offsets below in halfs)
#define OFF_WI1 0
#define OFF_WI2 16384
#define OFF_WE  32768
#define OFF_WO1 49152
#define WB_HALFS 114688
#define WB_BYTES (WB_HALFS*2)
#define WBOFF_COMPACT (4096 + Bn*MAXV*4)   // 266240
#define WBOFF_SMALL   2560

// 16B-granule XOR swizzle for a [64][256]-f16 LDS tile (indices in f16 units).
// colg = col>>3. XORing the low 3 granule bits with row&7 spreads the
// stride-512B column reads across all banks (conflict-free for b128).
__device__ __forceinline__ int swz8(int row, int colg) {
    return row*256 + (((colg & ~7) | ((colg ^ row) & 7)) << 3);
}
__device__ __forceinline__ int swzofs(int row, int col) {  // 8B-aligned accesses
    return swz8(row, col >> 3) + (col & 7);
}

// B-fragment loader: PRE = pre-converted fragment-contiguous f16 in ws
// (16B/lane, coalesced); fallback converts from f32 row-major on the fly.
template<bool PRE>
__device__ __forceinline__ f16x8 load_bfrag(const f16* __restrict__ WF,
                                            const float* __restrict__ W,
                                            int N, int NT, int kt, int nt, int l) {
    if constexpr (PRE) {
        return *(const f16x8*)(WF + ((kt*NT + nt)*64 + l)*8);
    } else {
        const int col = 16*nt + (l & 15);
        const int k0  = 32*kt + 8*(l >> 4);
        f16x8 r;
        #pragma unroll
        for (int j = 0; j < 8; ++j) r[j] = (f16)W[(k0 + j)*N + col];
        return r;
    }
}

// ---------------------------------------------------------------------------
// One-time weight conversion into B-fragment layout:
// frag(kt,nt): lane l, j=0..7 holds (f16)W[32kt + 8*(l>>4) + j][16nt + (l&15)]
// Blocks [0,56): prep.  Blocks [56,1056): valid-row ballot compaction.
// ---------------------------------------------------------------------------
__global__ __launch_bounds__(256)
void prepcount_kernel(const float* __restrict__ Wi1, const float* __restrict__ Wi2,
                      const float* __restrict__ We,  const float* __restrict__ Wo1,
                      f16* __restrict__ WB, const unsigned char* __restrict__ mask,
                      int* __restrict__ cnt, int* __restrict__ vlist) {
    const int blk = blockIdx.x;
    if (blk < 56) {
        int id = blk*256 + threadIdx.x;   // 0..14335
        const float* W; int NT, N; f16* WF; int fid;
        if (id < 2048)      { W = Wi1; NT = 8;  N = 128; WF = WB+OFF_WI1; fid = id; }
        else if (id < 4096) { W = Wi2; NT = 8;  N = 128; WF = WB+OFF_WI2; fid = id-2048; }
        else if (id < 6144) { W = We;  NT = 8;  N = 128; WF = WB+OFF_WE;  fid = id-4096; }
        else                { W = Wo1; NT = 16; N = 256; WF = WB+OFF_WO1; fid = id-6144; }
        int frag = fid >> 6, l = fid & 63;
        int nt = frag % NT, kt = frag / NT;
        int col = 16*nt + (l & 15), k0 = 32*kt + 8*(l >> 4);
        #pragma unroll
        for (int j = 0; j < 8; ++j) WF[frag*512 + l*8 + j] = (f16)W[(k0 + j)*N + col];
    } else {
        const int idx = (blk - 56)*256 + threadIdx.x;   // 0..255999
        const int b = idx / NCUBE, e = idx % NCUBE;
        const int k = e % Nn, ij = e / Nn, j = ij % Nn, i = ij / Nn;
        const bool v = (i < j) && (j < k) &&
                       mask[b*Nn+i] && mask[b*Nn+j] && mask[b*Nn+k];
        const unsigned long long m = __ballot(v);
        const int lane = threadIdx.x & 63;
        const int c = __popcll(m);
        int base = 0;
        if (lane == 0 && c) base = atomicAdd(&cnt[b], c);
        base = __shfl(base, 0);
        if (v) vlist[b*MAXV + base + __popcll(m & ((1ull<<lane)-1ull))] = e;
    }
}

// ---------------------------------------------------------------------------
// Sums kernel: stages 1-2 + masked exp-sum. 512 threads = 8 waves arranged as
// 2 row-groups (wr) x 4 col-slices (wc); wave covers rows [32wr,32wr+32),
// cols [32wc,32wc+32). COMPACT: rows gathered from vlist (all valid).
// ---------------------------------------------------------------------------
template<bool PRE, bool COMPACT>
__global__ __launch_bounds__(512, 8)
void sums_kernel(const float* __restrict__ x, const unsigned char* __restrict__ mask,
                 const float* __restrict__ Wi1, const float* __restrict__ bi1,
                 const float* __restrict__ Wi2, const float* __restrict__ bi2,
                 float* __restrict__ sums, const int* __restrict__ cnt,
                 const int* __restrict__ vlist, const f16* __restrict__ WB)
{
    const int tid = threadIdx.x;
    const int l = tid & 63, w = tid >> 6, lr = l & 15, lg = l >> 4;
    const int wr = w >> 2, wc = w & 3;
    int b, r0;
    if (COMPACT) { b = blockIdx.x / CBLK; r0 = (blockIdx.x % CBLK)*ROWS; if (r0 >= cnt[b]) return; }
    else         { b = blockIdx.x / BPB;  r0 = (blockIdx.x % BPB)*ROWS; }

    __shared__ __align__(16) f16 hb[ROWS*256];
    __shared__ int earr[ROWS];
    __shared__ unsigned char mlds[Nn];
    __shared__ int anyv;

    if (!COMPACT) { if (tid < Nn) mlds[tid] = mask[b*Nn + tid]; if (tid == 0) anyv = 0; }
    if (tid < ROWS) {
        if (COMPACT) { int r = r0 + tid; earr[tid] = (r < cnt[b]) ? vlist[b*MAXV + r] : -1; }
        else earr[tid] = r0 + tid;
    }
    __syncthreads();

    bool rv[2];
    if (!COMPACT) {
        bool any = false;
        #pragma unroll
        for (int mt = 0; mt < 2; ++mt) {
            int e = earr[32*wr + 16*mt + lr];
            int k = e % Nn, ij = e / Nn, j = ij % Nn, i = ij / Nn;
            rv[mt] = (i < j) && (j < k) && mlds[i] && mlds[j] && mlds[k];
            any |= rv[mt];
        }
        if (any) anyv = 1;
        __syncthreads();
        if (!anyv) return;
    } else {
        #pragma unroll
        for (int mt = 0; mt < 2; ++mt) rv[mt] = (earr[32*wr + 16*mt + lr] >= 0);
    }

    // phase A: gather x rows -> f16 LDS cols [128,256)
    #pragma unroll
    for (int p = 0; p < 4; ++p) {
        const int row = p*16 + (tid >> 5);
        const int c0  = (tid & 31)*4;
        int e = earr[row]; if (e < 0) e = 0;
        const float4 xv = *(const float4*)&x[((long)(b*NCUBE + e))*128 + c0];
        f16x4 v; v[0]=(f16)xv.x; v[1]=(f16)xv.y; v[2]=(f16)xv.z; v[3]=(f16)xv.w;
        *(f16x4*)&hb[swzofs(row, 128 + c0)] = v;
    }
    __syncthreads();

    // stage 1: h1 = relu(x @ Wi1 + bi1) -> cols [0,128)
    {
        f32x4 acc1[2][2];
        #pragma unroll
        for (int n = 0; n < 2; ++n) {
            const float4 bv = *(const float4*)(bi1 + 16*(2*wc + n) + 4*lg);
            #pragma unroll
            for (int mt = 0; mt < 2; ++mt) {
                acc1[mt][n][0]=bv.x; acc1[mt][n][1]=bv.y; acc1[mt][n][2]=bv.z; acc1[mt][n][3]=bv.w;
            }
        }
        #pragma unroll
        for (int kt = 0; kt < 4; ++kt) {
            f16x8 bf[2];
            #pragma unroll
            for (int n = 0; n < 2; ++n)
                bf[n] = load_bfrag<PRE>(WB+OFF_WI1, Wi1, 128, 8, kt, 2*wc+n, l);
            #pragma unroll
            for (int mt = 0; mt < 2; ++mt) {
                const f16x8 af = *(const f16x8*)&hb[swz8(32*wr + 16*mt + lr, 16 + 4*kt + lg)];
                #pragma unroll
                for (int n = 0; n < 2; ++n)
                    acc1[mt][n] = __builtin_amdgcn_mfma_f32_16x16x32_f16(bf[n], af, acc1[mt][n], 0, 0, 0);
            }
        }
        #pragma unroll
        for (int mt = 0; mt < 2; ++mt)
            #pragma unroll
            for (int n = 0; n < 2; ++n) {
                f16x4 v;
                #pragma unroll
                for (int r = 0; r < 4; ++r) v[r] = (f16)fmaxf(acc1[mt][n][r], 0.f);
                *(f16x4*)&hb[swzofs(32*wr + 16*mt + lr, 16*(2*wc + n) + 4*lg)] = v;
            }
    }
    __syncthreads();

    // stage 2: xf = h1 @ Wi2 + bi2
    f32x4 acc2[2][2];
    {
        #pragma unroll
        for (int n = 0; n < 2; ++n) {
            const float4 bv = *(const float4*)(bi2 + 16*(2*wc + n) + 4*lg);
            #pragma unroll
            for (int mt = 0; mt < 2; ++mt) {
                acc2[mt][n][0]=bv.x; acc2[mt][n][1]=bv.y; acc2[mt][n][2]=bv.z; acc2[mt][n][3]=bv.w;
            }
        }
        #pragma unroll
        for (int kt = 0; kt < 4; ++kt) {
            f16x8 bf[2];
            #pragma unroll
            for (int n = 0; n < 2; ++n)
                bf[n] = load_bfrag<PRE>(WB+OFF_WI2, Wi2, 128, 8, kt, 2*wc+n, l);
            #pragma unroll
            for (int mt = 0; mt < 2; ++mt) {
                const f16x8 af = *(const f16x8*)&hb[swz8(32*wr + 16*mt + lr, 4*kt + lg)];
                #pragma unroll
                for (int n = 0; n < 2; ++n)
                    acc2[mt][n] = __builtin_amdgcn_mfma_f32_16x16x32_f16(bf[n], af, acc2[mt][n], 0, 0, 0);
            }
        }
    }

    // masked exp-sum; reduce over 16 rows (lr) per wave, atomic per col
    float s[2][4] = {{0,0,0,0},{0,0,0,0}};
    #pragma unroll
    for (int mt = 0; mt < 2; ++mt)
        if (rv[mt])
            #pragma unroll
            for (int n = 0; n < 2; ++n)
                #pragma unroll
                for (int r = 0; r < 4; ++r) s[n][r] += __expf(acc2[mt][n][r]);
    #pragma unroll
    for (int n = 0; n < 2; ++n)
        #pragma unroll
        for (int r = 0; r < 4; ++r) {
            float v = s[n][r];
            v += __shfl_xor(v, 1); v += __shfl_xor(v, 2);
            v += __shfl_xor(v, 4); v += __shfl_xor(v, 8);
            if (lr == 0) atomicAdd(&sums[b*128 + 16*(2*wc + n) + 4*lg + r], v);
        }
}

// ---------------------------------------------------------------------------
// Full kernel: all 5 stages, all rows. 512 threads = 8 waves as 2 row-groups
// (wr: rows [32wr,32wr+32)) x 4 col-slices (wc: cols [32wc,32wc+32) of
// 128-wide stages, [64wc,64wc+64) of stage 4). Single f16 LDS tile (swizzled):
//   phA: x -> [128,256) | s1: h1 -> [0,128) | s2: xf(regs) -> [128,256)
//   s3: a*xi -> [0,128) | s4: K=256 over [a*xi | xf] | s5: 256->1 reduce.
// ---------------------------------------------------------------------------
template<bool PRE>
__global__ __launch_bounds__(512, 8)
void full_kernel(const float* __restrict__ x, const unsigned char* __restrict__ mask,
                 const float* __restrict__ Wi1, const float* __restrict__ bi1,
                 const float* __restrict__ Wi2, const float* __restrict__ bi2,
                 const float* __restrict__ We,
                 const float* __restrict__ Wo1, const float* __restrict__ bo1,
                 const float* __restrict__ Wo2, const float* __restrict__ bo2,
                 const float* __restrict__ sums, const f16* __restrict__ WB,
                 float* __restrict__ out)
{
    const int tid = threadIdx.x;
    const int l = tid & 63, w = tid >> 6, lr = l & 15, lg = l >> 4;
    const int wr = w >> 2, wc = w & 3;
    const int b = blockIdx.x / BPB;
    const int e0 = (blockIdx.x % BPB) * ROWS;

    __shared__ __align__(16) f16 hb[ROWS*256];
    __shared__ float red[8][32];
    __shared__ unsigned char mlds[Nn];

    if (tid < Nn) mlds[tid] = mask[b*Nn + tid];

    // phase A: x tile -> f16 LDS cols [128,256)
    #pragma unroll
    for (int p = 0; p < 4; ++p) {
        const int row = p*16 + (tid >> 5);
        const int c0  = (tid & 31)*4;
        const float4 xv = *(const float4*)&x[((long)(b*NCUBE + e0 + row))*128 + c0];
        f16x4 v; v[0]=(f16)xv.x; v[1]=(f16)xv.y; v[2]=(f16)xv.z; v[3]=(f16)xv.w;
        *(f16x4*)&hb[swzofs(row, 128 + c0)] = v;
    }
    __syncthreads();

    bool valid[2];
    #pragma unroll
    for (int mt = 0; mt < 2; ++mt) {
        int e = e0 + 32*wr + 16*mt + lr;
        int k = e % Nn, ij = e / Nn, j = ij % Nn, i = ij / Nn;
        valid[mt] = (i < j) && (j < k) && mlds[i] && mlds[j] && mlds[k];
    }

    // ---- stage 1: h1 = relu(x @ Wi1 + bi1) -> cols [0,128) ----
    {
        f32x4 acc1[2][2];
        #pragma unroll
        for (int n = 0; n < 2; ++n) {
            const float4 bv = *(const float4*)(bi1 + 16*(2*wc + n) + 4*lg);
            #pragma unroll
            for (int mt = 0; mt < 2; ++mt) {
                acc1[mt][n][0]=bv.x; acc1[mt][n][1]=bv.y; acc1[mt][n][2]=bv.z; acc1[mt][n][3]=bv.w;
            }
        }
        #pragma unroll
        for (int kt = 0; kt < 4; ++kt) {
            f16x8 bf[2];
            #pragma unroll
            for (int n = 0; n < 2; ++n)
                bf[n] = load_bfrag<PRE>(WB+OFF_WI1, Wi1, 128, 8, kt, 2*wc+n, l);
            #pragma unroll
            for (int mt = 0; mt < 2; ++mt) {
                const f16x8 af = *(const f16x8*)&hb[swz8(32*wr + 16*mt + lr, 16 + 4*kt + lg)];
                #pragma unroll
                for (int n = 0; n < 2; ++n)
                    acc1[mt][n] = __builtin_amdgcn_mfma_f32_16x16x32_f16(bf[n], af, acc1[mt][n], 0, 0, 0);
            }
        }
        #pragma unroll
        for (int mt = 0; mt < 2; ++mt)
            #pragma unroll
            for (int n = 0; n < 2; ++n) {
                f16x4 v;
                #pragma unroll
                for (int r = 0; r < 4; ++r) v[r] = (f16)fmaxf(acc1[mt][n][r], 0.f);
                *(f16x4*)&hb[swzofs(32*wr + 16*mt + lr, 16*(2*wc + n) + 4*lg)] = v;
            }
    }
    __syncthreads();

    // ---- stage 2: xf = h1 @ Wi2 + bi2 (kept in regs) -> cols [128,256) ----
    f32x4 acc2[2][2];
    {
        #pragma unroll
        for (int n = 0; n < 2; ++n) {
            const float4 bv = *(const float4*)(bi2 + 16*(2*wc + n) + 4*lg);
            #pragma unroll
            for (int mt = 0; mt < 2; ++mt) {
                acc2[mt][n][0]=bv.x; acc2[mt][n][1]=bv.y; acc2[mt][n][2]=bv.z; acc2[mt][n][3]=bv.w;
            }
        }
        #pragma unroll
        for (int kt = 0; kt < 4; ++kt) {
            f16x8 bf[2];
            #pragma unroll
            for (int n = 0; n < 2; ++n)
                bf[n] = load_bfrag<PRE>(WB+OFF_WI2, Wi2, 128, 8, kt, 2*wc+n, l);
            #pragma unroll
            for (int mt = 0; mt < 2; ++mt) {
                const f16x8 af = *(const f16x8*)&hb[swz8(32*wr + 16*mt + lr, 4*kt + lg)];
                #pragma unroll
                for (int n = 0; n < 2; ++n)
                    acc2[mt][n] = __builtin_amdgcn_mfma_f32_16x16x32_f16(bf[n], af, acc2[mt][n], 0, 0, 0);
            }
        }
        // x region is dead after s1's barrier: write xf there.
        #pragma unroll
        for (int mt = 0; mt < 2; ++mt)
            #pragma unroll
            for (int n = 0; n < 2; ++n) {
                f16x4 v;
                #pragma unroll
                for (int r = 0; r < 4; ++r) v[r] = (f16)acc2[mt][n][r];
                *(f16x4*)&hb[swzofs(32*wr + 16*mt + lr, 128 + 16*(2*wc + n) + 4*lg)] = v;
            }
    }
    __syncthreads();

    // ---- stage 3: xi = relu(xf @ We); a*xi -> cols [0,128) ----
    {
        f32x4 acc3[2][2];
        #pragma unroll
        for (int mt = 0; mt < 2; ++mt)
            #pragma unroll
            for (int n = 0; n < 2; ++n) { acc3[mt][n][0]=0.f; acc3[mt][n][1]=0.f; acc3[mt][n][2]=0.f; acc3[mt][n][3]=0.f; }
        #pragma unroll
        for (int kt = 0; kt < 4; ++kt) {
            f16x8 ef[2];
            #pragma unroll
            for (int n = 0; n < 2; ++n)
                ef[n] = load_bfrag<PRE>(WB+OFF_WE, We, 128, 8, kt, 2*wc+n, l);
            #pragma unroll
            for (int mt = 0; mt < 2; ++mt) {
                const f16x8 af = *(const f16x8*)&hb[swz8(32*wr + 16*mt + lr, 16 + 4*kt + lg)];
                #pragma unroll
                for (int n = 0; n < 2; ++n)
                    acc3[mt][n] = __builtin_amdgcn_mfma_f32_16x16x32_f16(ef[n], af, acc3[mt][n], 0, 0, 0);
            }
        }
        const float4 sv = *(const float4*)(sums + b*128 + 16*(2*wc) + 4*lg);     // n=0 cols
        const float4 sw = *(const float4*)(sums + b*128 + 16*(2*wc+1) + 4*lg);   // n=1 cols
        const float rinv[2][4] = {{1.f/sv.x, 1.f/sv.y, 1.f/sv.z, 1.f/sv.w},
                                  {1.f/sw.x, 1.f/sw.y, 1.f/sw.z, 1.f/sw.w}};
        #pragma unroll
        for (int mt = 0; mt < 2; ++mt)
            #pragma unroll
            for (int n = 0; n < 2; ++n) {
                f16x4 v;
                #pragma unroll
                for (int r = 0; r < 4; ++r) {
                    const float aa = valid[mt] ? __expf(acc2[mt][n][r]) * rinv[n][r] : 0.0f;
                    v[r] = (f16)(aa * fmaxf(acc3[mt][n][r], 0.f));
                }
                *(f16x4*)&hb[swzofs(32*wr + 16*mt + lr, 16*(2*wc + n) + 4*lg)] = v;
            }
    }
    __syncthreads();

    // ---- stage 4: g = relu(h @ Wo1 + bo1), K=256 over h=[a*xi | xf] ----
    f32x4 acc4[2][4];
    #pragma unroll
    for (int n = 0; n < 4; ++n) {
        const float4 bv = *(const float4*)(bo1 + 16*(4*wc + n) + 4*lg);
        #pragma unroll
        for (int mt = 0; mt < 2; ++mt) {
            acc4[mt][n][0]=bv.x; acc4[mt][n][1]=bv.y; acc4[mt][n][2]=bv.z; acc4[mt][n][3]=bv.w;
        }
    }
    #pragma unroll
    for (int kt = 0; kt < 8; ++kt) {
        f16x8 of[4];
        #pragma unroll
        for (int n = 0; n < 4; ++n)
            of[n] = load_bfrag<PRE>(WB+OFF_WO1, Wo1, 256, 16, kt, 4*wc+n, l);
        #pragma unroll
        for (int mt = 0; mt < 2; ++mt) {
            const f16x8 af = *(const f16x8*)&hb[swz8(32*wr + 16*mt + lr, 4*kt + lg)];
            #pragma unroll
            for (int n = 0; n < 4; ++n)
                acc4[mt][n] = __builtin_amdgcn_mfma_f32_16x16x32_f16(of[n], af, acc4[mt][n], 0, 0, 0);
        }
    }

    // ---- stage 5: out = relu(g) @ Wo2 + bo2, reduce 256 -> 1 per row ----
    {
        float outp[2] = {0.f, 0.f};
        #pragma unroll
        for (int n = 0; n < 4; ++n) {
            const float4 wv = *(const float4*)(Wo2 + 16*(4*wc + n) + 4*lg);
            #pragma unroll
            for (int mt = 0; mt < 2; ++mt) {
                outp[mt] += fmaxf(acc4[mt][n][0], 0.f)*wv.x + fmaxf(acc4[mt][n][1], 0.f)*wv.y
                          + fmaxf(acc4[mt][n][2], 0.f)*wv.z + fmaxf(acc4[mt][n][3], 0.f)*wv.w;
            }
        }
        #pragma unroll
        for (int mt = 0; mt < 2; ++mt) {
            outp[mt] += __shfl_xor(outp[mt], 16);
            outp[mt] += __shfl_xor(outp[mt], 32);
        }
        if (l < 16) {
            #pragma unroll
            for (int mt = 0; mt < 2; ++mt) red[w][16*mt + lr] = outp[mt];
        }
        __syncthreads();
        if (tid < ROWS) {
            const int rg = (tid >> 5)*4, rr = tid & 31;
            out[(long)b*NCUBE + e0 + tid] =
                red[rg+0][rr] + red[rg+1][rr] + red[rg+2][rr] + red[rg+3][rr] + bo2[0];
        }
    }
}

extern "C" void kernel_launch(void* const* d_in, const int* in_sizes, int n_in,
                              void* d_out, int out_size, void* d_ws, size_t ws_size,
                              hipStream_t stream) {
    const float*         x    = (const float*)d_in[0];
    const unsigned char* mask = (const unsigned char*)d_in[1];
    const float* Wi1 = (const float*)d_in[2];
    const float* bi1 = (const float*)d_in[3];
    const float* Wi2 = (const float*)d_in[4];
    const float* bi2 = (const float*)d_in[5];
    const float* We  = (const float*)d_in[6];
    const float* Wo1 = (const float*)d_in[7];
    const float* bo1 = (const float*)d_in[8];
    const float* Wo2 = (const float*)d_in[9];
    const float* bo2 = (const float*)d_in[10];
    float* out  = (float*)d_out;
    float* sums = (float*)d_ws;
    int*   cnt   = (int*)((char*)d_ws + 2048);
    int*   vlist = (int*)((char*)d_ws + 4096);

    const bool compact = ws_size >= (size_t)(WBOFF_COMPACT + WB_BYTES);
    const size_t wboff = compact ? WBOFF_COMPACT : WBOFF_SMALL;
    const bool pre     = ws_size >= wboff + WB_BYTES;
    f16* WB = (f16*)((char*)d_ws + wboff);

    hipMemsetAsync(d_ws, 0, 2048 + Bn*sizeof(int), stream);

    if (compact) {
        prepcount_kernel<<<1056, 256, 0, stream>>>(Wi1, Wi2, We, Wo1, WB, mask, cnt, vlist);
        sums_kernel<true, true><<<Bn*CBLK, 512, 0, stream>>>(x, mask, Wi1, bi1, Wi2, bi2,
                                                             sums, cnt, vlist, WB);
        full_kernel<true><<<Bn*BPB, 512, 0, stream>>>(x, mask, Wi1, bi1, Wi2, bi2, We,
                                                      Wo1, bo1, Wo2, bo2, sums, WB, out);
    } else if (pre) {
        prepcount_kernel<<<56, 256, 0, stream>>>(Wi1, Wi2, We, Wo1, WB, mask, cnt, vlist);
        sums_kernel<true, false><<<Bn*BPB, 512, 0, stream>>>(x, mask, Wi1, bi1, Wi2, bi2,
                                                             sums, cnt, vlist, WB);
        full_kernel<true><<<Bn*BPB, 512, 0, stream>>>(x, mask, Wi1, bi1, Wi2, bi2, We,
                                                      Wo1, bo1, Wo2, bo2, sums, WB, out);
    } else {
        sums_kernel<false, false><<<Bn*BPB, 512, 0, stream>>>(x, mask, Wi1, bi1, Wi2, bi2,
                                                              sums, cnt, vlist, WB);
        full_kernel<false><<<Bn*BPB, 512, 0, stream>>>(x, mask, Wi1, bi1, Wi2, bi2, We,
                                                       Wo1, bo1, Wo2, bo2, sums, WB, out);
    }
}

// Round 5
// 266.633 us; speedup vs baseline: 1.2233x; 1.2233x over previous
//
#include <hip/hip_runtime.h>

#define Bn 4
#define Nn 40
#define NCUBE 64000   // 40^3
#define ROWS 64       // rows per tile
#define BPB  1000     // full/dense-sums blocks per batch
#define MAXV 16384    // valid-row list capacity per batch (>= C(40,3)=9880)
#define CBLK 160      // compact-sums blocks per batch

typedef _Float16 f16;
typedef __attribute__((ext_vector_type(8))) _Float16 f16x8;
typedef __attribute__((ext_vector_type(4))) _Float16 f16x4;
typedef __attribute__((ext_vector_type(4))) float f32x4;

// ---------------- workspace layout (bytes) ----------------
// 0      : sums[Bn*128] f32
// 2048   : cnt[Bn] int
// 4096   : vlist[Bn*MAXV] int        (compact tier only)
// WBOFF  : f16 weight fragments (offsets below in halfs)
#define OFF_WI1 0
#define OFF_WI2 16384
#define OFF_WE  32768
#define OFF_WO1 49152
#define WB_HALFS 114688
#define WB_BYTES (WB_HALFS*2)
#define WBOFF_COMPACT (4096 + Bn*MAXV*4)   // 266240
#define WBOFF_SMALL   2560

// 16B-granule XOR swizzle for a [64][256]-f16 LDS tile (indices in f16 units).
__device__ __forceinline__ int swz8(int row, int colg) {
    return row*256 + (((colg & ~7) | ((colg ^ row) & 7)) << 3);
}
__device__ __forceinline__ int swzofs(int row, int col) {  // 8B-aligned accesses
    return swz8(row, col >> 3) + (col & 7);
}

// B-fragment loader: PRE = pre-converted fragment-contiguous f16 in ws
// (16B/lane, coalesced); fallback converts from f32 row-major on the fly.
template<bool PRE>
__device__ __forceinline__ f16x8 load_bfrag(const f16* __restrict__ WF,
                                            const float* __restrict__ W,
                                            int N, int NT, int kt, int nt, int l) {
    if constexpr (PRE) {
        return *(const f16x8*)(WF + ((kt*NT + nt)*64 + l)*8);
    } else {
        const int col = 16*nt + (l & 15);
        const int k0  = 32*kt + 8*(l >> 4);
        f16x8 r;
        #pragma unroll
        for (int j = 0; j < 8; ++j) r[j] = (f16)W[(k0 + j)*N + col];
        return r;
    }
}

// ---------------------------------------------------------------------------
// One-time weight conversion into B-fragment layout + valid-row compaction.
// frag(kt,nt): lane l, j=0..7 holds (f16)W[32kt + 8*(l>>4) + j][16nt + (l&15)]
// Blocks [0,56): prep.  Blocks [56,1056): ballot compaction.
// ---------------------------------------------------------------------------
__global__ __launch_bounds__(256)
void prepcount_kernel(const float* __restrict__ Wi1, const float* __restrict__ Wi2,
                      const float* __restrict__ We,  const float* __restrict__ Wo1,
                      f16* __restrict__ WB, const unsigned char* __restrict__ mask,
                      int* __restrict__ cnt, int* __restrict__ vlist) {
    const int blk = blockIdx.x;
    if (blk < 56) {
        int id = blk*256 + threadIdx.x;   // 0..14335
        const float* W; int NT, N; f16* WF; int fid;
        if (id < 2048)      { W = Wi1; NT = 8;  N = 128; WF = WB+OFF_WI1; fid = id; }
        else if (id < 4096) { W = Wi2; NT = 8;  N = 128; WF = WB+OFF_WI2; fid = id-2048; }
        else if (id < 6144) { W = We;  NT = 8;  N = 128; WF = WB+OFF_WE;  fid = id-4096; }
        else                { W = Wo1; NT = 16; N = 256; WF = WB+OFF_WO1; fid = id-6144; }
        int frag = fid >> 6, l = fid & 63;
        int nt = frag % NT, kt = frag / NT;
        int col = 16*nt + (l & 15), k0 = 32*kt + 8*(l >> 4);
        #pragma unroll
        for (int j = 0; j < 8; ++j) WF[frag*512 + l*8 + j] = (f16)W[(k0 + j)*N + col];
    } else {
        const int idx = (blk - 56)*256 + threadIdx.x;   // 0..255999
        const int b = idx / NCUBE, e = idx % NCUBE;
        const int k = e % Nn, ij = e / Nn, j = ij % Nn, i = ij / Nn;
        const bool v = (i < j) && (j < k) &&
                       mask[b*Nn+i] && mask[b*Nn+j] && mask[b*Nn+k];
        const unsigned long long m = __ballot(v);
        const int lane = threadIdx.x & 63;
        const int c = __popcll(m);
        int base = 0;
        if (lane == 0 && c) base = atomicAdd(&cnt[b], c);
        base = __shfl(base, 0);
        if (v) vlist[b*MAXV + base + __popcll(m & ((1ull<<lane)-1ull))] = e;
    }
}

// ---------------------------------------------------------------------------
// Sums kernel: stages 1-2 + masked exp-sum. 512 threads = 8 waves as
// 2 row-groups (wr) x 4 col-slices (wc). COMPACT: rows gathered from vlist.
// launch_bounds min-waves = 4: 128-VGPR cap, NO SPILL (R4 lesson: 8 -> 64 cap
// -> 290MB scratch traffic, the whole kernel's time).
// ---------------------------------------------------------------------------
template<bool PRE, bool COMPACT>
__global__ __launch_bounds__(512, 4)
void sums_kernel(const float* __restrict__ x, const unsigned char* __restrict__ mask,
                 const float* __restrict__ Wi1, const float* __restrict__ bi1,
                 const float* __restrict__ Wi2, const float* __restrict__ bi2,
                 float* __restrict__ sums, const int* __restrict__ cnt,
                 const int* __restrict__ vlist, const f16* __restrict__ WB)
{
    const int tid = threadIdx.x;
    const int l = tid & 63, w = tid >> 6, lr = l & 15, lg = l >> 4;
    const int wr = w >> 2, wc = w & 3;
    int b, r0;
    if (COMPACT) { b = blockIdx.x / CBLK; r0 = (blockIdx.x % CBLK)*ROWS; if (r0 >= cnt[b]) return; }
    else         { b = blockIdx.x / BPB;  r0 = (blockIdx.x % BPB)*ROWS; }

    __shared__ __align__(16) f16 hb[ROWS*256];
    __shared__ int earr[ROWS];
    __shared__ unsigned char mlds[Nn];
    __shared__ int anyv;

    if (!COMPACT) { if (tid < Nn) mlds[tid] = mask[b*Nn + tid]; if (tid == 0) anyv = 0; }
    if (tid < ROWS) {
        if (COMPACT) { int r = r0 + tid; earr[tid] = (r < cnt[b]) ? vlist[b*MAXV + r] : -1; }
        else earr[tid] = r0 + tid;
    }
    __syncthreads();

    bool rv[2];
    if (!COMPACT) {
        bool any = false;
        #pragma unroll
        for (int mt = 0; mt < 2; ++mt) {
            int e = earr[32*wr + 16*mt + lr];
            int k = e % Nn, ij = e / Nn, j = ij % Nn, i = ij / Nn;
            rv[mt] = (i < j) && (j < k) && mlds[i] && mlds[j] && mlds[k];
            any |= rv[mt];
        }
        if (any) anyv = 1;
        __syncthreads();
        if (!anyv) return;
    } else {
        #pragma unroll
        for (int mt = 0; mt < 2; ++mt) rv[mt] = (earr[32*wr + 16*mt + lr] >= 0);
    }

    // phase A: gather x rows -> f16 LDS cols [128,256)
    #pragma unroll
    for (int p = 0; p < 4; ++p) {
        const int row = p*16 + (tid >> 5);
        const int c0  = (tid & 31)*4;
        int e = earr[row]; if (e < 0) e = 0;
        const float4 xv = *(const float4*)&x[((long)(b*NCUBE + e))*128 + c0];
        f16x4 v; v[0]=(f16)xv.x; v[1]=(f16)xv.y; v[2]=(f16)xv.z; v[3]=(f16)xv.w;
        *(f16x4*)&hb[swzofs(row, 128 + c0)] = v;
    }
    __syncthreads();

    // stage 1: h1 = relu(x @ Wi1 + bi1) -> cols [0,128)
    {
        f32x4 acc1[2][2];
        #pragma unroll
        for (int n = 0; n < 2; ++n) {
            const float4 bv = *(const float4*)(bi1 + 16*(2*wc + n) + 4*lg);
            #pragma unroll
            for (int mt = 0; mt < 2; ++mt) {
                acc1[mt][n][0]=bv.x; acc1[mt][n][1]=bv.y; acc1[mt][n][2]=bv.z; acc1[mt][n][3]=bv.w;
            }
        }
        #pragma unroll
        for (int kt = 0; kt < 4; ++kt) {
            f16x8 bf[2];
            #pragma unroll
            for (int n = 0; n < 2; ++n)
                bf[n] = load_bfrag<PRE>(WB+OFF_WI1, Wi1, 128, 8, kt, 2*wc+n, l);
            #pragma unroll
            for (int mt = 0; mt < 2; ++mt) {
                const f16x8 af = *(const f16x8*)&hb[swz8(32*wr + 16*mt + lr, 16 + 4*kt + lg)];
                #pragma unroll
                for (int n = 0; n < 2; ++n)
                    acc1[mt][n] = __builtin_amdgcn_mfma_f32_16x16x32_f16(bf[n], af, acc1[mt][n], 0, 0, 0);
            }
        }
        #pragma unroll
        for (int mt = 0; mt < 2; ++mt)
            #pragma unroll
            for (int n = 0; n < 2; ++n) {
                f16x4 v;
                #pragma unroll
                for (int r = 0; r < 4; ++r) v[r] = (f16)fmaxf(acc1[mt][n][r], 0.f);
                *(f16x4*)&hb[swzofs(32*wr + 16*mt + lr, 16*(2*wc + n) + 4*lg)] = v;
            }
    }
    __syncthreads();

    // stage 2: xf = h1 @ Wi2 + bi2
    f32x4 acc2[2][2];
    {
        #pragma unroll
        for (int n = 0; n < 2; ++n) {
            const float4 bv = *(const float4*)(bi2 + 16*(2*wc + n) + 4*lg);
            #pragma unroll
            for (int mt = 0; mt < 2; ++mt) {
                acc2[mt][n][0]=bv.x; acc2[mt][n][1]=bv.y; acc2[mt][n][2]=bv.z; acc2[mt][n][3]=bv.w;
            }
        }
        #pragma unroll
        for (int kt = 0; kt < 4; ++kt) {
            f16x8 bf[2];
            #pragma unroll
            for (int n = 0; n < 2; ++n)
                bf[n] = load_bfrag<PRE>(WB+OFF_WI2, Wi2, 128, 8, kt, 2*wc+n, l);
            #pragma unroll
            for (int mt = 0; mt < 2; ++mt) {
                const f16x8 af = *(const f16x8*)&hb[swz8(32*wr + 16*mt + lr, 4*kt + lg)];
                #pragma unroll
                for (int n = 0; n < 2; ++n)
                    acc2[mt][n] = __builtin_amdgcn_mfma_f32_16x16x32_f16(bf[n], af, acc2[mt][n], 0, 0, 0);
            }
        }
    }

    // masked exp-sum; reduce over 16 rows (lr) per wave, atomic per col
    float s[2][4] = {{0,0,0,0},{0,0,0,0}};
    #pragma unroll
    for (int mt = 0; mt < 2; ++mt)
        if (rv[mt])
            #pragma unroll
            for (int n = 0; n < 2; ++n)
                #pragma unroll
                for (int r = 0; r < 4; ++r) s[n][r] += __expf(acc2[mt][n][r]);
    #pragma unroll
    for (int n = 0; n < 2; ++n)
        #pragma unroll
        for (int r = 0; r < 4; ++r) {
            float v = s[n][r];
            v += __shfl_xor(v, 1); v += __shfl_xor(v, 2);
            v += __shfl_xor(v, 4); v += __shfl_xor(v, 8);
            if (lr == 0) atomicAdd(&sums[b*128 + 16*(2*wc + n) + 4*lg + r], v);
        }
}

// ---------------------------------------------------------------------------
// Full kernel: all 5 stages, all rows. 512 threads = 8 waves as 2 row-groups
// (wr) x 4 col-slices (wc). Single f16 LDS tile (swizzled):
//   phA: x -> [128,256) | s1: h1 -> [0,128) | s2: xf(regs) -> [128,256),
//   acc2 converted IN PLACE to a = valid?exp(xf)/sum:0 (drops rinv liveness)
//   s3: a*xi -> [0,128) | s4: K=256 over [a*xi | xf] | s5: 256->1 reduce.
// min-waves=4 -> 128 VGPR cap: no spill (R4: min-waves=8 spilled 290MB).
// ---------------------------------------------------------------------------
template<bool PRE>
__global__ __launch_bounds__(512, 4)
void full_kernel(const float* __restrict__ x, const unsigned char* __restrict__ mask,
                 const float* __restrict__ Wi1, const float* __restrict__ bi1,
                 const float* __restrict__ Wi2, const float* __restrict__ bi2,
                 const float* __restrict__ We,
                 const float* __restrict__ Wo1, const float* __restrict__ bo1,
                 const float* __restrict__ Wo2, const float* __restrict__ bo2,
                 const float* __restrict__ sums, const f16* __restrict__ WB,
                 float* __restrict__ out)
{
    const int tid = threadIdx.x;
    const int l = tid & 63, w = tid >> 6, lr = l & 15, lg = l >> 4;
    const int wr = w >> 2, wc = w & 3;
    const int b = blockIdx.x / BPB;
    const int e0 = (blockIdx.x % BPB) * ROWS;

    __shared__ __align__(16) f16 hb[ROWS*256];
    __shared__ float red[8][32];
    __shared__ unsigned char mlds[Nn];

    if (tid < Nn) mlds[tid] = mask[b*Nn + tid];

    // phase A: x tile -> f16 LDS cols [128,256)
    #pragma unroll
    for (int p = 0; p < 4; ++p) {
        const int row = p*16 + (tid >> 5);
        const int c0  = (tid & 31)*4;
        const float4 xv = *(const float4*)&x[((long)(b*NCUBE + e0 + row))*128 + c0];
        f16x4 v; v[0]=(f16)xv.x; v[1]=(f16)xv.y; v[2]=(f16)xv.z; v[3]=(f16)xv.w;
        *(f16x4*)&hb[swzofs(row, 128 + c0)] = v;
    }
    __syncthreads();

    bool valid[2];
    #pragma unroll
    for (int mt = 0; mt < 2; ++mt) {
        int e = e0 + 32*wr + 16*mt + lr;
        int k = e % Nn, ij = e / Nn, j = ij % Nn, i = ij / Nn;
        valid[mt] = (i < j) && (j < k) && mlds[i] && mlds[j] && mlds[k];
    }

    // ---- stage 1: h1 = relu(x @ Wi1 + bi1) -> cols [0,128) ----
    {
        f32x4 acc1[2][2];
        #pragma unroll
        for (int n = 0; n < 2; ++n) {
            const float4 bv = *(const float4*)(bi1 + 16*(2*wc + n) + 4*lg);
            #pragma unroll
            for (int mt = 0; mt < 2; ++mt) {
                acc1[mt][n][0]=bv.x; acc1[mt][n][1]=bv.y; acc1[mt][n][2]=bv.z; acc1[mt][n][3]=bv.w;
            }
        }
        #pragma unroll
        for (int kt = 0; kt < 4; ++kt) {
            f16x8 bf[2];
            #pragma unroll
            for (int n = 0; n < 2; ++n)
                bf[n] = load_bfrag<PRE>(WB+OFF_WI1, Wi1, 128, 8, kt, 2*wc+n, l);
            #pragma unroll
            for (int mt = 0; mt < 2; ++mt) {
                const f16x8 af = *(const f16x8*)&hb[swz8(32*wr + 16*mt + lr, 16 + 4*kt + lg)];
                #pragma unroll
                for (int n = 0; n < 2; ++n)
                    acc1[mt][n] = __builtin_amdgcn_mfma_f32_16x16x32_f16(bf[n], af, acc1[mt][n], 0, 0, 0);
            }
        }
        #pragma unroll
        for (int mt = 0; mt < 2; ++mt)
            #pragma unroll
            for (int n = 0; n < 2; ++n) {
                f16x4 v;
                #pragma unroll
                for (int r = 0; r < 4; ++r) v[r] = (f16)fmaxf(acc1[mt][n][r], 0.f);
                *(f16x4*)&hb[swzofs(32*wr + 16*mt + lr, 16*(2*wc + n) + 4*lg)] = v;
            }
    }
    __syncthreads();

    // ---- stage 2: xf = h1 @ Wi2 + bi2; write xf -> [128,256); acc2 := a ----
    f32x4 acc2[2][2];
    {
        #pragma unroll
        for (int n = 0; n < 2; ++n) {
            const float4 bv = *(const float4*)(bi2 + 16*(2*wc + n) + 4*lg);
            #pragma unroll
            for (int mt = 0; mt < 2; ++mt) {
                acc2[mt][n][0]=bv.x; acc2[mt][n][1]=bv.y; acc2[mt][n][2]=bv.z; acc2[mt][n][3]=bv.w;
            }
        }
        #pragma unroll
        for (int kt = 0; kt < 4; ++kt) {
            f16x8 bf[2];
            #pragma unroll
            for (int n = 0; n < 2; ++n)
                bf[n] = load_bfrag<PRE>(WB+OFF_WI2, Wi2, 128, 8, kt, 2*wc+n, l);
            #pragma unroll
            for (int mt = 0; mt < 2; ++mt) {
                const f16x8 af = *(const f16x8*)&hb[swz8(32*wr + 16*mt + lr, 4*kt + lg)];
                #pragma unroll
                for (int n = 0; n < 2; ++n)
                    acc2[mt][n] = __builtin_amdgcn_mfma_f32_16x16x32_f16(bf[n], af, acc2[mt][n], 0, 0, 0);
            }
        }
        // x region is dead after s1's barrier: write xf there.
        #pragma unroll
        for (int mt = 0; mt < 2; ++mt)
            #pragma unroll
            for (int n = 0; n < 2; ++n) {
                f16x4 v;
                #pragma unroll
                for (int r = 0; r < 4; ++r) v[r] = (f16)acc2[mt][n][r];
                *(f16x4*)&hb[swzofs(32*wr + 16*mt + lr, 128 + 16*(2*wc + n) + 4*lg)] = v;
            }
        // convert acc2 in place to softmax weight a (retires rinv/sv early)
        #pragma unroll
        for (int n = 0; n < 2; ++n) {
            const float4 sv = *(const float4*)(sums + b*128 + 16*(2*wc + n) + 4*lg);
            const float rinv[4] = {1.f/sv.x, 1.f/sv.y, 1.f/sv.z, 1.f/sv.w};
            #pragma unroll
            for (int mt = 0; mt < 2; ++mt)
                #pragma unroll
                for (int r = 0; r < 4; ++r)
                    acc2[mt][n][r] = valid[mt] ? __expf(acc2[mt][n][r]) * rinv[r] : 0.0f;
        }
    }
    __syncthreads();

    // ---- stage 3: xi = relu(xf @ We); a*xi -> cols [0,128) ----
    {
        f32x4 acc3[2][2];
        #pragma unroll
        for (int mt = 0; mt < 2; ++mt)
            #pragma unroll
            for (int n = 0; n < 2; ++n) { acc3[mt][n][0]=0.f; acc3[mt][n][1]=0.f; acc3[mt][n][2]=0.f; acc3[mt][n][3]=0.f; }
        #pragma unroll
        for (int kt = 0; kt < 4; ++kt) {
            f16x8 ef[2];
            #pragma unroll
            for (int n = 0; n < 2; ++n)
                ef[n] = load_bfrag<PRE>(WB+OFF_WE, We, 128, 8, kt, 2*wc+n, l);
            #pragma unroll
            for (int mt = 0; mt < 2; ++mt) {
                const f16x8 af = *(const f16x8*)&hb[swz8(32*wr + 16*mt + lr, 16 + 4*kt + lg)];
                #pragma unroll
                for (int n = 0; n < 2; ++n)
                    acc3[mt][n] = __builtin_amdgcn_mfma_f32_16x16x32_f16(ef[n], af, acc3[mt][n], 0, 0, 0);
            }
        }
        #pragma unroll
        for (int mt = 0; mt < 2; ++mt)
            #pragma unroll
            for (int n = 0; n < 2; ++n) {
                f16x4 v;
                #pragma unroll
                for (int r = 0; r < 4; ++r)
                    v[r] = (f16)(acc2[mt][n][r] * fmaxf(acc3[mt][n][r], 0.f));
                *(f16x4*)&hb[swzofs(32*wr + 16*mt + lr, 16*(2*wc + n) + 4*lg)] = v;
            }
    }
    __syncthreads();

    // ---- stage 4: g = relu(h @ Wo1 + bo1), K=256 over h=[a*xi | xf] ----
    f32x4 acc4[2][4];
    #pragma unroll
    for (int n = 0; n < 4; ++n) {
        const float4 bv = *(const float4*)(bo1 + 16*(4*wc + n) + 4*lg);
        #pragma unroll
        for (int mt = 0; mt < 2; ++mt) {
            acc4[mt][n][0]=bv.x; acc4[mt][n][1]=bv.y; acc4[mt][n][2]=bv.z; acc4[mt][n][3]=bv.w;
        }
    }
    #pragma unroll
    for (int kt = 0; kt < 8; ++kt) {
        f16x8 of[4];
        #pragma unroll
        for (int n = 0; n < 4; ++n)
            of[n] = load_bfrag<PRE>(WB+OFF_WO1, Wo1, 256, 16, kt, 4*wc+n, l);
        #pragma unroll
        for (int mt = 0; mt < 2; ++mt) {
            const f16x8 af = *(const f16x8*)&hb[swz8(32*wr + 16*mt + lr, 4*kt + lg)];
            #pragma unroll
            for (int n = 0; n < 4; ++n)
                acc4[mt][n] = __builtin_amdgcn_mfma_f32_16x16x32_f16(of[n], af, acc4[mt][n], 0, 0, 0);
        }
    }

    // ---- stage 5: out = relu(g) @ Wo2 + bo2, reduce 256 -> 1 per row ----
    {
        float outp[2] = {0.f, 0.f};
        #pragma unroll
        for (int n = 0; n < 4; ++n) {
            const float4 wv = *(const float4*)(Wo2 + 16*(4*wc + n) + 4*lg);
            #pragma unroll
            for (int mt = 0; mt < 2; ++mt) {
                outp[mt] += fmaxf(acc4[mt][n][0], 0.f)*wv.x + fmaxf(acc4[mt][n][1], 0.f)*wv.y
                          + fmaxf(acc4[mt][n][2], 0.f)*wv.z + fmaxf(acc4[mt][n][3], 0.f)*wv.w;
            }
        }
        #pragma unroll
        for (int mt = 0; mt < 2; ++mt) {
            outp[mt] += __shfl_xor(outp[mt], 16);
            outp[mt] += __shfl_xor(outp[mt], 32);
        }
        if (l < 16) {
            #pragma unroll
            for (int mt = 0; mt < 2; ++mt) red[w][16*mt + lr] = outp[mt];
        }
        __syncthreads();
        if (tid < ROWS) {
            const int rg = (tid >> 5)*4, rr = tid & 31;
            out[(long)b*NCUBE + e0 + tid] =
                red[rg+0][rr] + red[rg+1][rr] + red[rg+2][rr] + red[rg+3][rr] + bo2[0];
        }
    }
}

extern "C" void kernel_launch(void* const* d_in, const int* in_sizes, int n_in,
                              void* d_out, int out_size, void* d_ws, size_t ws_size,
                              hipStream_t stream) {
    const float*         x    = (const float*)d_in[0];
    const unsigned char* mask = (const unsigned char*)d_in[1];
    const float* Wi1 = (const float*)d_in[2];
    const float* bi1 = (const float*)d_in[3];
    const float* Wi2 = (const float*)d_in[4];
    const float* bi2 = (const float*)d_in[5];
    const float* We  = (const float*)d_in[6];
    const float* Wo1 = (const float*)d_in[7];
    const float* bo1 = (const float*)d_in[8];
    const float* Wo2 = (const float*)d_in[9];
    const float* bo2 = (const float*)d_in[10];
    float* out  = (float*)d_out;
    float* sums = (float*)d_ws;
    int*   cnt   = (int*)((char*)d_ws + 2048);
    int*   vlist = (int*)((char*)d_ws + 4096);

    const bool compact = ws_size >= (size_t)(WBOFF_COMPACT + WB_BYTES);
    const size_t wboff = compact ? WBOFF_COMPACT : WBOFF_SMALL;
    const bool pre     = ws_size >= wboff + WB_BYTES;
    f16* WB = (f16*)((char*)d_ws + wboff);

    hipMemsetAsync(d_ws, 0, 2048 + Bn*sizeof(int), stream);

    if (compact) {
        prepcount_kernel<<<1056, 256, 0, stream>>>(Wi1, Wi2, We, Wo1, WB, mask, cnt, vlist);
        sums_kernel<true, true><<<Bn*CBLK, 512, 0, stream>>>(x, mask, Wi1, bi1, Wi2, bi2,
                                                             sums, cnt, vlist, WB);
        full_kernel<true><<<Bn*BPB, 512, 0, stream>>>(x, mask, Wi1, bi1, Wi2, bi2, We,
                                                      Wo1, bo1, Wo2, bo2, sums, WB, out);
    } else if (pre) {
        prepcount_kernel<<<56, 256, 0, stream>>>(Wi1, Wi2, We, Wo1, WB, mask, cnt, vlist);
        sums_kernel<true, false><<<Bn*BPB, 512, 0, stream>>>(x, mask, Wi1, bi1, Wi2, bi2,
                                                             sums, cnt, vlist, WB);
        full_kernel<true><<<Bn*BPB, 512, 0, stream>>>(x, mask, Wi1, bi1, Wi2, bi2, We,
                                                      Wo1, bo1, Wo2, bo2, sums, WB, out);
    } else {
        sums_kernel<false, false><<<Bn*BPB, 512, 0, stream>>>(x, mask, Wi1, bi1, Wi2, bi2,
                                                              sums, cnt, vlist, WB);
        full_kernel<false><<<Bn*BPB, 512, 0, stream>>>(x, mask, Wi1, bi1, Wi2, bi2, We,
                                                       Wo1, bo1, Wo2, bo2, sums, WB, out);
    }
}